// Round 3
// baseline (278.222 us; speedup 1.0000x reference)
//
#include <hip/hip_runtime.h>
#include <stdint.h>

// out[p,b,o] = sum_i x*w0 + (1-x)*w1,  x,w in {0,1}
//            = sum_iw popc( (x & w0) | (~x & w1) )   -- one v_bfi_b32 + one
//              accumulating v_bcnt per word. Exact.
//
// R11: three-kernel split. R8's limiter was NOT LDS (broadcast b128 is ~3cyc)
// but the w-stream pattern: 256B granules at 8KB stride, whole-machine
// aligned -> ~52% of HBM peak (fills hit 85% on linear). So:
//   pack_x : x -> 2 MiB bitset (unchanged, proven).
//   pack_w : LINEAR 512 MiB sweep of w -> 16 MiB packed wp[m][p][iw][o].
//            Each block reads a 32-row x 8KB tile contiguously, ballots
//            64-col masks into 8KB LDS, transposes bits to words.
//   evo    : reads packed wp (L2/L3-resident) directly to registers
//            (8 coalesced dwords per 4-iword window), x via double-buffered
//            xs in LDS (broadcast reads), ONE barrier per stage.
// Fallback to the R8 single-pass kernel if ws_size < 18 MiB.

#define NP 16
#define NB 512
#define NI 2048
#define NO 2048
#define JW 64               // u32 words per i-row
#define OG 64               // o-columns per evo block
#define NOG (NO / OG)       // 32
#define STW 16              // i-words per stage
#define NSTAGE (JW / STW)   // 4
#define XP_WORDS (NP * NB * JW)        // 524288  u32 = 2 MiB
#define WP_WORDS (2 * NP * JW * NO)    // 4194304 u32 = 16 MiB

// ---------------------------------------------------------------- pack_x ----
__global__ __launch_bounds__(256) void pack_x_kernel(const float* __restrict__ x,
                                                     uint32_t* __restrict__ xp) {
    const int gtid = blockIdx.x * 256 + threadIdx.x;
    const int row  = gtid >> 6;     // p*NB + b
    const int lane = gtid & 63;
    const float* src = x + (size_t)row * NI;
    unsigned long long* dst = (unsigned long long*)(xp + (size_t)row * JW);
#pragma unroll 4
    for (int k = 0; k < NI / 64; ++k) {
        const float v = src[k * 64 + lane];
        const unsigned long long m = __ballot(v != 0.0f);
        if (lane == 0) dst[k] = m;
    }
}

// ---------------------------------------------------------------- pack_w ----
// block = (m*16+p, ib): rows ib*32..+31, all 2048 cols. Linear 256 KB read.
__global__ __launch_bounds__(256) void pack_w_kernel(const float* __restrict__ w,
                                                     uint32_t* __restrict__ wp) {
    __shared__ unsigned long long masks[32][32];   // [row][cgroup], 8 KB

    const int tid  = threadIdx.x;
    const int lane = tid & 63;
    const int wvv  = tid >> 6;          // wave 0..3
    const int bid  = blockIdx.x;        // (m*16+p)*64 + ib
    const int ib   = bid & 63;
    const int mp   = bid >> 6;

    const float* src = w + (size_t)mp * ((size_t)NI * NO) + (size_t)(ib * 32) * NO;

    // phase A: wave walks whole rows (wvv, wvv+4, ...) in 256B linear steps
#pragma unroll 1
    for (int r8 = 0; r8 < 8; ++r8) {
        const int row = wvv + 4 * r8;
        const float* rs = src + (size_t)row * NO + lane;
#pragma unroll
        for (int cg = 0; cg < 32; ++cg) {
            const unsigned long long m = __ballot(rs[cg * 64] != 0.0f);
            if (lane == 0) masks[row][cg] = m;
        }
    }
    __syncthreads();

    // phase B: thread t -> packed words for o = t*8..t*8+7 (iw = ib)
    const int cg   = tid >> 3;          // o>>6
    const int half = (tid >> 2) & 1;    // (o>>5)&1
    const int sh   = (tid & 3) * 8;     // o&31 base bit
    const uint32_t* m32 = (const uint32_t*)masks;
    uint32_t aw[8];
#pragma unroll
    for (int j = 0; j < 8; ++j) aw[j] = 0;
#pragma unroll
    for (int k = 0; k < 32; ++k) {
        const uint32_t byte = (m32[(k * 32 + cg) * 2 + half] >> sh) & 0xFFu;
        aw[0] |= ((byte >> 0) & 1u) << k;
        aw[1] |= ((byte >> 1) & 1u) << k;
        aw[2] |= ((byte >> 2) & 1u) << k;
        aw[3] |= ((byte >> 3) & 1u) << k;
        aw[4] |= ((byte >> 4) & 1u) << k;
        aw[5] |= ((byte >> 5) & 1u) << k;
        aw[6] |= ((byte >> 6) & 1u) << k;
        aw[7] |= ((byte >> 7) & 1u) << k;
    }
    uint32_t* dst = wp + (size_t)mp * (JW * NO) + (size_t)ib * NO + tid * 8;
    *(uint4*)dst       = *(uint4*)&aw[0];
    *(uint4*)(dst + 4) = *(uint4*)&aw[4];
}

// ---------------------------------------------------------- shared macros ----
// issue this thread's 8 x-words (stage s_) into xv[8]
#define XISSUE(s_) do {                                                        \
    const uint32_t* _xsrc = xp + ((size_t)p * NB + (tid >> 1)) * JW            \
                          + (s_) * STW + (tid & 1) * 8;                        \
    *(uint4*)&xv[0] = *(const uint4*)_xsrc;                                    \
    *(uint4*)&xv[4] = *(const uint4*)(_xsrc + 4);                              \
} while (0)

// ------------------------------------------------------------- evo (new) ----
// write xv into double-buffered xs[b_]
#define XWRITE(b_) do {                                                        \
    *(uint4*)&xs[b_][tid >> 1][(tid & 1) * 8]     = *(uint4*)&xv[0];           \
    *(uint4*)&xs[b_][tid >> 1][(tid & 1) * 8 + 4] = *(uint4*)&xv[4];           \
} while (0)

// load a 4-iword window of packed w (both mats) straight from global (L2)
#define WLOADW(d0, d1, iwb) do {                                               \
    _Pragma("unroll")                                                          \
    for (int _j = 0; _j < 4; ++_j) {                                           \
        d0[_j] = wpc0[(size_t)((iwb) + _j) * NO];                              \
        d1[_j] = wpc1[(size_t)((iwb) + _j) * NO];                              \
    }                                                                          \
} while (0)

// compute 8 row-pairs (half h) of window win from xs[b_] (broadcast reads)
#define HALFW(w0r_, w1r_, win, h, b_) do {                                     \
    _Pragma("unroll")                                                          \
    for (int _t = 0; _t < 8; ++_t) {                                           \
        const int _pr = (h) * 8 + _t;                                          \
        const uint4 _xa = *(const uint4*)&xs[b_][wv * 32 + 2 * _pr][(win) * 4];\
        const uint4 _xb = *(const uint4*)&xs[b_][wv * 32 + 2 * _pr + 1][(win) * 4]; \
        uint32_t _tA = __popc((_xa.x & w0r_[0]) | (~_xa.x & w1r_[0]))          \
                     + __popc((_xa.y & w0r_[1]) | (~_xa.y & w1r_[1]))          \
                     + __popc((_xa.z & w0r_[2]) | (~_xa.z & w1r_[2]))          \
                     + __popc((_xa.w & w0r_[3]) | (~_xa.w & w1r_[3]));         \
        uint32_t _tB = __popc((_xb.x & w0r_[0]) | (~_xb.x & w1r_[0]))          \
                     + __popc((_xb.y & w0r_[1]) | (~_xb.y & w1r_[1]))          \
                     + __popc((_xb.z & w0r_[2]) | (~_xb.z & w1r_[2]))          \
                     + __popc((_xb.w & w0r_[3]) | (~_xb.w & w1r_[3]));         \
        acc[_pr] += _tA + (_tB << 16);                                         \
    }                                                                          \
} while (0)

// windows alternate reg sets A/B; w for win+1 prefetched during win.
// xs double-buffered -> ONE barrier per stage; XWRITE mid-stage (xv ready).
#define STAGEP(s_, more_) do {                                                 \
    if (more_) XISSUE((s_) + 1);                                               \
    WLOADW(w0B, w1B, (s_) * STW + 4);                                          \
    HALFW(w0A, w1A, 0, 0, (s_) & 1); HALFW(w0A, w1A, 0, 1, (s_) & 1);          \
    WLOADW(w0A, w1A, (s_) * STW + 8);                                          \
    if (more_) XWRITE(((s_) + 1) & 1);                                         \
    HALFW(w0B, w1B, 1, 0, (s_) & 1); HALFW(w0B, w1B, 1, 1, (s_) & 1);          \
    WLOADW(w0B, w1B, (s_) * STW + 12);                                         \
    HALFW(w0A, w1A, 2, 0, (s_) & 1); HALFW(w0A, w1A, 2, 1, (s_) & 1);          \
    if (more_) WLOADW(w0A, w1A, ((s_) + 1) * STW);                             \
    HALFW(w0B, w1B, 3, 0, (s_) & 1); HALFW(w0B, w1B, 3, 1, (s_) & 1);          \
    if (more_) __syncthreads();                                                \
} while (0)

__global__ __launch_bounds__(1024) void evo_pk(const uint32_t* __restrict__ wp,
                                               const uint32_t* __restrict__ xp,
                                               float* __restrict__ out) {
    __shared__ uint32_t xs[2][NB][STW];        // 64 KB, double-buffered x bits

    const int tid  = threadIdx.x;
    const int lane = tid & 63;
    const int wv   = __builtin_amdgcn_readfirstlane(tid >> 6);  // 0..15
    const int p    = blockIdx.x >> 5;   // 0..15
    const int og   = blockIdx.x & 31;   // 0..31
    const int col  = og * OG + lane;

    const uint32_t* wpc0 = wp + (size_t)p * (JW * NO) + col;
    const uint32_t* wpc1 = wpc0 + (size_t)NP * (JW * NO);

    uint32_t acc[16];   // low16 = row 2t, high16 = row 2t+1 (<=2048, exact)
#pragma unroll
    for (int t = 0; t < 16; ++t) acc[t] = 0;

    uint32_t xv[8], w0A[4], w1A[4], w0B[4], w1B[4];

    // prologue: stage-0 x + window-0 w
    XISSUE(0);
    WLOADW(w0A, w1A, 0);
    XWRITE(0);
    __syncthreads();

    STAGEP(0, true);
    STAGEP(1, true);
    STAGEP(2, true);
    STAGEP(3, false);

    float* obase = out + ((size_t)p * NB + wv * 32) * NO + (size_t)og * OG + lane;
#pragma unroll
    for (int t = 0; t < 16; ++t) {
        obase[(size_t)(2 * t) * NO]     = (float)(acc[t] & 0xFFFFu);
        obase[(size_t)(2 * t + 1) * NO] = (float)(acc[t] >> 16);
    }
}

// ------------------------------------------------- fallback: R8 single-pass ----
#define WISSUE_F(dst, gi, b) do {                                              \
    const float* _s = ((b) < 4 ? wcol0 : wcol1)                                \
                    + (size_t)((gi) * 32 + ((b) & 3) * 8) * NO;                \
    _Pragma("unroll")                                                          \
    for (int _u = 0; _u < 8; ++_u) dst[_u] = __float_as_uint(_s[(size_t)_u * NO]); \
} while (0)

#define WEXTRACT_F(src, b) do {                                                \
    uint32_t _pt = 0;                                                          \
    _Pragma("unroll")                                                          \
    for (int _u = 0; _u < 8; ++_u) _pt |= ((src[_u] >> 23) & 1u) << _u;        \
    if ((b) < 4) nwd0 |= _pt << (((b) & 3) * 8);                               \
    else         nwd1 |= _pt << (((b) & 3) * 8);                               \
} while (0)

#define XWRITE_F() do {                                                        \
    *(uint4*)&xsf[tid >> 1][(tid & 1) * 8]     = *(uint4*)&xv[0];              \
    *(uint4*)&xsf[tid >> 1][(tid & 1) * 8 + 4] = *(uint4*)&xv[4];              \
} while (0)

#define WWIN_F(cur_, win) do {                                                 \
    _Pragma("unroll")                                                          \
    for (int _j = 0; _j < 4; ++_j) {                                           \
        const uint2 _p2 = *(const uint2*)&wbuf[cur_][(win) * 4 + _j][lane][0]; \
        w0r[_j] = _p2.x; w1r[_j] = _p2.y;                                      \
    }                                                                          \
} while (0)

#define HALF_F(win, h) do {                                                    \
    _Pragma("unroll")                                                          \
    for (int _t = 0; _t < 8; ++_t) {                                           \
        const int _pr = (h) * 8 + _t;                                          \
        const uint4 _xa = *(const uint4*)&xsf[wv * 32 + 2 * _pr][(win) * 4];   \
        const uint4 _xb = *(const uint4*)&xsf[wv * 32 + 2 * _pr + 1][(win) * 4]; \
        uint32_t _tA = __popc((_xa.x & w0r[0]) | (~_xa.x & w1r[0]))            \
                     + __popc((_xa.y & w0r[1]) | (~_xa.y & w1r[1]))            \
                     + __popc((_xa.z & w0r[2]) | (~_xa.z & w1r[2]))            \
                     + __popc((_xa.w & w0r[3]) | (~_xa.w & w1r[3]));           \
        uint32_t _tB = __popc((_xb.x & w0r[0]) | (~_xb.x & w1r[0]))            \
                     + __popc((_xb.y & w0r[1]) | (~_xb.y & w1r[1]))            \
                     + __popc((_xb.z & w0r[2]) | (~_xb.z & w1r[2]))            \
                     + __popc((_xb.w & w0r[3]) | (~_xb.w & w1r[3]));           \
        acc[_pr] += _tA + (_tB << 16);                                         \
    }                                                                          \
} while (0)

#define STAGE_F(s_, cur_, more_) do {                                          \
    const int _gi1 = ((s_) + 1) * STW + wv;                                    \
    if (more_) { XISSUE((s_) + 1); nwd0 = 0; nwd1 = 0;                         \
                 WISSUE_F(va, _gi1, 0); WISSUE_F(vb, _gi1, 1); }               \
    WWIN_F(cur_, 0); HALF_F(0, 0);                                             \
    if (more_) { WEXTRACT_F(va, 0); WISSUE_F(va, _gi1, 2); }                   \
    HALF_F(0, 1);                                                              \
    if (more_) { WEXTRACT_F(vb, 1); WISSUE_F(vb, _gi1, 3); }                   \
    WWIN_F(cur_, 1); HALF_F(1, 0);                                             \
    if (more_) { WEXTRACT_F(va, 2); WISSUE_F(va, _gi1, 4); }                   \
    HALF_F(1, 1);                                                              \
    if (more_) { WEXTRACT_F(vb, 3); WISSUE_F(vb, _gi1, 5);                     \
                 wbuf[(cur_) ^ 1][wv][lane][0] = nwd0; }                       \
    WWIN_F(cur_, 2); HALF_F(2, 0);                                             \
    if (more_) { WEXTRACT_F(va, 4); WISSUE_F(va, _gi1, 6); }                   \
    HALF_F(2, 1);                                                              \
    if (more_) { WEXTRACT_F(vb, 5); WISSUE_F(vb, _gi1, 7); }                   \
    WWIN_F(cur_, 3); HALF_F(3, 0);                                             \
    if (more_) { WEXTRACT_F(va, 6); }                                          \
    HALF_F(3, 1);                                                              \
    if (more_) { WEXTRACT_F(vb, 7); wbuf[(cur_) ^ 1][wv][lane][1] = nwd1;      \
                 __syncthreads(); XWRITE_F(); __syncthreads(); }               \
} while (0)

__global__ __launch_bounds__(1024) void evo_f(const float* __restrict__ w,
                                              const uint32_t* __restrict__ xp,
                                              float* __restrict__ out) {
    __shared__ uint32_t wbuf[2][STW][OG][2];   // 16 KB
    __shared__ uint32_t xsf[NB][STW];          // 32 KB

    const int tid  = threadIdx.x;
    const int lane = tid & 63;
    const int wv   = __builtin_amdgcn_readfirstlane(tid >> 6);
    const int p    = blockIdx.x >> 5;
    const int og   = blockIdx.x & 31;

    const size_t wq = (size_t)NI * NO;
    const float* wcol0 = w + (size_t)p * wq + (size_t)(og * OG + lane);
    const float* wcol1 = wcol0 + (size_t)NP * wq;

    uint32_t acc[16];
#pragma unroll
    for (int t = 0; t < 16; ++t) acc[t] = 0;

    uint32_t xv[8], va[8], vb[8], w0r[4], w1r[4];
    uint32_t nwd0 = 0, nwd1 = 0;

    XISSUE(0);
    {
        const int gi = wv;
        WISSUE_F(va, gi, 0); WISSUE_F(vb, gi, 1);
        WEXTRACT_F(va, 0);   WISSUE_F(va, gi, 2);
        WEXTRACT_F(vb, 1);   WISSUE_F(vb, gi, 3);
        WEXTRACT_F(va, 2);   WISSUE_F(va, gi, 4);
        WEXTRACT_F(vb, 3);   WISSUE_F(vb, gi, 5);
        wbuf[0][wv][lane][0] = nwd0;
        WEXTRACT_F(va, 4);   WISSUE_F(va, gi, 6);
        WEXTRACT_F(vb, 5);   WISSUE_F(vb, gi, 7);
        WEXTRACT_F(va, 6);
        WEXTRACT_F(vb, 7);
        wbuf[0][wv][lane][1] = nwd1;
    }
    XWRITE_F();
    __syncthreads();

    STAGE_F(0, 0, true);
    STAGE_F(1, 1, true);
    STAGE_F(2, 0, true);
    STAGE_F(3, 1, false);

    float* obase = out + ((size_t)p * NB + wv * 32) * NO + (size_t)og * OG + lane;
#pragma unroll
    for (int t = 0; t < 16; ++t) {
        obase[(size_t)(2 * t) * NO]     = (float)(acc[t] & 0xFFFFu);
        obase[(size_t)(2 * t + 1) * NO] = (float)(acc[t] >> 16);
    }
}

// ---------------------------------------------------------------- launch ----
extern "C" void kernel_launch(void* const* d_in, const int* in_sizes, int n_in,
                              void* d_out, int out_size, void* d_ws, size_t ws_size,
                              hipStream_t stream) {
    const float* x = (const float*)d_in[0];   // (16,512,2048) fp32 {0,1}
    const float* w = (const float*)d_in[1];   // (2,16,1,2048,2048) fp32 {0,1}
    float* out     = (float*)d_out;           // (16,512,2048) fp32
    uint32_t* xp   = (uint32_t*)d_ws;         // 2 MiB packed x
    uint32_t* wpp  = xp + XP_WORDS;           // 16 MiB packed w

    pack_x_kernel<<<dim3((NP * NB * 64) / 256), dim3(256), 0, stream>>>(x, xp);

    if (ws_size >= (size_t)(XP_WORDS + WP_WORDS) * 4) {
        pack_w_kernel<<<dim3(2 * NP * (NI / 32)), dim3(256), 0, stream>>>(w, wpp);
        evo_pk<<<dim3(NP * NOG), dim3(1024), 0, stream>>>(wpp, xp, out);
    } else {
        evo_f<<<dim3(NP * NOG), dim3(1024), 0, stream>>>(w, xp, out);
    }
}

// Round 5
// 256.427 us; speedup vs baseline: 1.0850x; 1.0850x over previous
//
#include <hip/hip_runtime.h>
#include <stdint.h>

// out[p,b,o] = sum_i x*w0 + (1-x)*w1,  x,w in {0,1}
//            = sum_iw popc( (x & w0) | (~x & w1) )   -- one v_bfi_b32 + one
//              accumulating v_bcnt per word. Exact.
//
// R13: R8 structure with x moved from LDS broadcasts to the SCALAR pipe,
// via constant-address-space (AS4) loads instead of R12's inline asm (which
// crashed the backend). x words are wave-uniform (base = f(blockIdx, wv via
// readfirstlane), offsets compile-time) -> clang selects s_load_dwordx4;
// values live in SGPRs and feed v_bfi_b32 as its one legal scalar operand
// (zero extra VALU -- unlike R9's readlane, zero LDS -- unlike R8).
//   - xs[] LDS array, XISSUE/XWRITE and one barrier/stage DELETED.
//   - vmcnt FIFO now contains ONLY the w prefetch bursts.
//   - LDS: wbuf only (16 KB). ~56 VGPR -> 2 blocks/CU, 32 waves/CU.
//   Block 1024 thr = (p, og-64), grid 512. acc u16-packed pairs (exact).

#define NP 16
#define NB 512
#define NI 2048
#define NO 2048
#define JW 64               // u32 words per i-row
#define OG 64               // o-columns per block
#define NOG (NO / OG)       // 32
#define STW 16              // i-words per stage
#define NSTAGE (JW / STW)   // 4

typedef uint32_t u32x4 __attribute__((ext_vector_type(4)));
typedef const __attribute__((address_space(4))) u32x4 kconst4;

__global__ __launch_bounds__(256) void pack_x_kernel(const float* __restrict__ x,
                                                     uint32_t* __restrict__ xp) {
    const int gtid = blockIdx.x * 256 + threadIdx.x;
    const int row  = gtid >> 6;     // p*NB + b
    const int lane = gtid & 63;
    const float* src = x + (size_t)row * NI;
    unsigned long long* dst = (unsigned long long*)(xp + (size_t)row * JW);
#pragma unroll 4
    for (int k = 0; k < NI / 64; ++k) {
        const float v = src[k * 64 + lane];
        const unsigned long long m = __ballot(v != 0.0f);
        if (lane == 0) dst[k] = m;
    }
}

// issue 8-row w burst b (0..3 = mat0 rows, 4..7 = mat1 rows) of i-word gi
#define WISSUE(dst, gi, b) do {                                                \
    const float* _s = ((b) < 4 ? wcol0 : wcol1)                                \
                    + (size_t)((gi) * 32 + ((b) & 3) * 8) * NO;                \
    _Pragma("unroll")                                                          \
    for (int _u = 0; _u < 8; ++_u) dst[_u] = __float_as_uint(_s[(size_t)_u * NO]); \
} while (0)

// fold burst b's 8 loaded floats into bits (b&3)*8.. of nwd0/nwd1
#define WEXTRACT(src, b) do {                                                  \
    uint32_t _pt = 0;                                                          \
    _Pragma("unroll")                                                          \
    for (int _u = 0; _u < 8; ++_u) _pt |= ((src[_u] >> 23) & 1u) << _u;        \
    if ((b) < 4) nwd0 |= _pt << (((b) & 3) * 8);                               \
    else         nwd1 |= _pt << (((b) & 3) * 8);                               \
} while (0)

// load the 4-iword w window for window `win` from wbuf[cur]
#define WWIN(cur_, win) do {                                                   \
    _Pragma("unroll")                                                          \
    for (int _j = 0; _j < 4; ++_j) {                                           \
        const uint2 _p2 = *(const uint2*)&wbuf[cur_][(win) * 4 + _j][lane][0]; \
        w0r[_j] = _p2.x; w1r[_j] = _p2.y;                                      \
    }                                                                          \
} while (0)

// 8 row-pairs (half h) of window win of stage s_; x via AS4 scalar loads
// (uniform address -> s_load_dwordx4, result in SGPRs, feeds bfi directly).
// xq element index: row * (JW/4) + s_*4 + win, all compile-time except base.
#define HALF(s_, win, h) do {                                                  \
    _Pragma("unroll")                                                          \
    for (int _t = 0; _t < 8; ++_t) {                                           \
        const int _pr = (h) * 8 + _t;                                          \
        const u32x4 _xa = xq[(2 * _pr) * (JW / 4) + (s_) * 4 + (win)];         \
        const u32x4 _xb = xq[(2 * _pr + 1) * (JW / 4) + (s_) * 4 + (win)];     \
        uint32_t _tA = __popc((_xa.x & w0r[0]) | (~_xa.x & w1r[0]))            \
                     + __popc((_xa.y & w0r[1]) | (~_xa.y & w1r[1]))            \
                     + __popc((_xa.z & w0r[2]) | (~_xa.z & w1r[2]))            \
                     + __popc((_xa.w & w0r[3]) | (~_xa.w & w1r[3]));           \
        uint32_t _tB = __popc((_xb.x & w0r[0]) | (~_xb.x & w1r[0]))            \
                     + __popc((_xb.y & w0r[1]) | (~_xb.y & w1r[1]))            \
                     + __popc((_xb.z & w0r[2]) | (~_xb.z & w1r[2]))            \
                     + __popc((_xb.w & w0r[3]) | (~_xb.w & w1r[3]));           \
        acc[_pr] += _tA + (_tB << 16);                                         \
    }                                                                          \
} while (0)

// one pipeline stage: compute stage s_ from wbuf[cur_] while prefetching
// stage s_+1's w (2 rotating 8-reg slots, extraction deferred >= half-window).
// ONE barrier per stage (wbuf double-buffered; x needs none).
#define STAGE(s_, cur_, more_) do {                                            \
    const int _gi1 = ((s_) + 1) * STW + wv;                                    \
    if (more_) { nwd0 = 0; nwd1 = 0;                                           \
                 WISSUE(va, _gi1, 0); WISSUE(vb, _gi1, 1); }                   \
    WWIN(cur_, 0); HALF(s_, 0, 0);                                             \
    if (more_) { WEXTRACT(va, 0); WISSUE(va, _gi1, 2); }                       \
    HALF(s_, 0, 1);                                                            \
    if (more_) { WEXTRACT(vb, 1); WISSUE(vb, _gi1, 3); }                       \
    WWIN(cur_, 1); HALF(s_, 1, 0);                                             \
    if (more_) { WEXTRACT(va, 2); WISSUE(va, _gi1, 4); }                       \
    HALF(s_, 1, 1);                                                            \
    if (more_) { WEXTRACT(vb, 3); WISSUE(vb, _gi1, 5);                         \
                 wbuf[(cur_) ^ 1][wv][lane][0] = nwd0; }                       \
    WWIN(cur_, 2); HALF(s_, 2, 0);                                             \
    if (more_) { WEXTRACT(va, 4); WISSUE(va, _gi1, 6); }                       \
    HALF(s_, 2, 1);                                                            \
    if (more_) { WEXTRACT(vb, 5); WISSUE(vb, _gi1, 7); }                       \
    WWIN(cur_, 3); HALF(s_, 3, 0);                                             \
    if (more_) { WEXTRACT(va, 6); }                                            \
    HALF(s_, 3, 1);                                                            \
    if (more_) { WEXTRACT(vb, 7); wbuf[(cur_) ^ 1][wv][lane][1] = nwd1;        \
                 __syncthreads(); }                                            \
} while (0)

__global__ __launch_bounds__(1024) void evo_main(const float* __restrict__ w,
                                                 const uint32_t* __restrict__ xp,
                                                 float* __restrict__ out) {
    __shared__ uint32_t wbuf[2][STW][OG][2];   // 16 KB, double-buffered w bits

    const int tid  = threadIdx.x;
    const int lane = tid & 63;
    const int wv   = __builtin_amdgcn_readfirstlane(tid >> 6);  // 0..15
    const int p    = blockIdx.x >> 5;   // 0..15
    const int og   = blockIdx.x & 31;   // 0..31

    const size_t wq = (size_t)NI * NO;
    const float* wcol0 = w + (size_t)p * wq + (size_t)(og * OG + lane);
    const float* wcol1 = wcol0 + (size_t)NP * wq;
    // wave-uniform constant-AS base: this wave's 32 x-rows (s_load path)
    const kconst4* xq = (const kconst4*)(uintptr_t)
        (xp + ((size_t)p * NB + (size_t)wv * 32) * JW);

    uint32_t acc[16];   // low16 = row 2t, high16 = row 2t+1 (<=2048, exact)
#pragma unroll
    for (int t = 0; t < 16; ++t) acc[t] = 0;

    uint32_t va[8], vb[8], w0r[4], w1r[4];
    uint32_t nwd0 = 0, nwd1 = 0;

    // ---- prologue: stage-0 w (i-word wv), 2-slot burst rotation ----
    {
        const int gi = wv;
        WISSUE(va, gi, 0); WISSUE(vb, gi, 1);
        WEXTRACT(va, 0);   WISSUE(va, gi, 2);
        WEXTRACT(vb, 1);   WISSUE(vb, gi, 3);
        WEXTRACT(va, 2);   WISSUE(va, gi, 4);
        WEXTRACT(vb, 3);   WISSUE(vb, gi, 5);
        wbuf[0][wv][lane][0] = nwd0;
        WEXTRACT(va, 4);   WISSUE(va, gi, 6);
        WEXTRACT(vb, 5);   WISSUE(vb, gi, 7);
        WEXTRACT(va, 6);
        WEXTRACT(vb, 7);
        wbuf[0][wv][lane][1] = nwd1;
    }
    __syncthreads();

    // ---- 4 stages; last one compute-only ----
    STAGE(0, 0, true);
    STAGE(1, 1, true);
    STAGE(2, 0, true);
    STAGE(3, 1, false);

    // ---- epilogue: unpack u16 pairs, coalesced stores ----
    float* obase = out + ((size_t)p * NB + wv * 32) * NO + (size_t)og * OG + lane;
#pragma unroll
    for (int t = 0; t < 16; ++t) {
        obase[(size_t)(2 * t) * NO]     = (float)(acc[t] & 0xFFFFu);
        obase[(size_t)(2 * t + 1) * NO] = (float)(acc[t] >> 16);
    }
}

extern "C" void kernel_launch(void* const* d_in, const int* in_sizes, int n_in,
                              void* d_out, int out_size, void* d_ws, size_t ws_size,
                              hipStream_t stream) {
    const float* x = (const float*)d_in[0];   // (16,512,2048) fp32 {0,1}
    const float* w = (const float*)d_in[1];   // (2,16,1,2048,2048) fp32 {0,1}
    float* out     = (float*)d_out;           // (16,512,2048) fp32
    uint32_t* xp   = (uint32_t*)d_ws;         // 2 MB packed x

    pack_x_kernel<<<dim3((NP * NB * 64) / 256), dim3(256), 0, stream>>>(x, xp);
    evo_main<<<dim3(NP * NOG), dim3(1024), 0, stream>>>(w, xp, out);
}

// Round 6
// 231.064 us; speedup vs baseline: 1.2041x; 1.1098x over previous
//
#include <hip/hip_runtime.h>
#include <stdint.h>

// out[p,b,o] = sum_i x*w0 + (1-x)*w1,  x,w in {0,1}
//            = sum_i x*(w0-w1) + sum_i w1
// R14: MFMA formulation. d = w0-w1 in {-1,0,1} (bf16-exact), x in {0,1}
// (bf16-exact), fp32 accumulation of integers <= 2048 -> EXACT result.
// The R8 popc structure floored at ~160us regardless of where w/x came
// from (R9-R13 ablations); MFMA moves the entire bit-compute onto the idle
// matrix pipes and leaves a pure HBM w-stream.
//   evo_mfma: grid 512 = 16 p x 32 o-tiles(64), block 512 thr = 8 waves.
//   Per wave: m-rows wv*64..+63 as 4 m-frags x 4 n-frags of 16x16x32 bf16
//   MFMA, K = 2048 in 64 steps of 32.
//   Per step: wave wv streams w rows wv*4..+3 (both mats, 256B coalesced
//   strips), converts to bf16 d in-reg, stages 32x64 d-tile in LDS
//   (double-buffered, 10KB); A-frags expanded on the fly from packed-x
//   bits (2MB, L2-resident); colsum(w1) accumulated per-thread.
//   2-step-ahead prefetch; barriers are raw s_barrier + lgkmcnt(0) ONLY
//   (vmcnt never drained -> w FIFO stays >=12 deep across barriers).

#define NP 16
#define NB 512
#define NI 2048
#define NO 2048
#define JW 64               // u32 words per i-row in xp
#define OT 64               // o-columns per block
#define KS 32               // k-rows per step
#define NST (NI / KS)       // 64 steps

typedef __attribute__((ext_vector_type(8))) short short8;
typedef __attribute__((ext_vector_type(4))) float f32x4;

__global__ __launch_bounds__(256) void pack_x_kernel(const float* __restrict__ x,
                                                     uint32_t* __restrict__ xp) {
    const int gtid = blockIdx.x * 256 + threadIdx.x;
    const int row  = gtid >> 6;     // p*NB + b
    const int lane = gtid & 63;
    const float* src = x + (size_t)row * NI;
    unsigned long long* dst = (unsigned long long*)(xp + (size_t)row * JW);
#pragma unroll 4
    for (int k = 0; k < NI / 64; ++k) {
        const float v = src[k * 64 + lane];
        const unsigned long long m = __ballot(v != 0.0f);
        if (lane == 0) dst[k] = m;
    }
}

// ---- step macros (reg sets passed explicitly; all indexing compile-time) ----

// issue next x-words (4 rows' step-words) and bump
#define XISS(xw) do {                                                          \
    xw[0] = xn[0]; xw[1] = xn[1024]; xw[2] = xn[2048]; xw[3] = xn[3072];       \
    xn += 1;                                                                   \
} while (0)

// issue next w rows (4 rows x both mats) and bump
#define WISS(wr) do {                                                          \
    wr[0] = w0n[0];      wr[1] = w0n[NO];                                      \
    wr[2] = w0n[2 * NO]; wr[3] = w0n[3 * NO];                                  \
    wr[4] = w1n[0];      wr[5] = w1n[NO];                                      \
    wr[6] = w1n[2 * NO]; wr[7] = w1n[3 * NO];                                  \
    w0n += KS * NO; w1n += KS * NO;                                            \
} while (0)

// convert w regs -> bf16 d, accumulate colsum(w1), write 4 contiguous bf16
#define WCVT(wr, b_) do {                                                      \
    cs += wr[4] + wr[5] + wr[6] + wr[7];                                       \
    const float d0 = wr[0] - wr[4], d1 = wr[1] - wr[5];                        \
    const float d2 = wr[2] - wr[6], d3 = wr[3] - wr[7];                        \
    uint2 _st;                                                                 \
    _st.x = (__float_as_uint(d0) >> 16) | (__float_as_uint(d1) & 0xFFFF0000u); \
    _st.y = (__float_as_uint(d2) >> 16) | (__float_as_uint(d3) & 0xFFFF0000u); \
    *(uint2*)&bds[b_][lane][wvid * 4] = _st;                                   \
} while (0)

// expand A-frags (4 m-tiles) from packed-x words: bit -> bf16 {0,1}
#define AEXP(afr, xw) do {                                                     \
    _Pragma("unroll")                                                          \
    for (int _mi = 0; _mi < 4; ++_mi) {                                        \
        const uint32_t _by = (xw[_mi] >> shamt) & 0xFFu;                       \
        union { uint32_t u[4]; short8 s; } _cv;                                \
        _cv.u[0] = (_by & 1u   ? 0x3F80u : 0u) | (_by & 2u   ? 0x3F800000u : 0u); \
        _cv.u[1] = (_by & 4u   ? 0x3F80u : 0u) | (_by & 8u   ? 0x3F800000u : 0u); \
        _cv.u[2] = (_by & 16u  ? 0x3F80u : 0u) | (_by & 32u  ? 0x3F800000u : 0u); \
        _cv.u[3] = (_by & 64u  ? 0x3F80u : 0u) | (_by & 128u ? 0x3F800000u : 0u); \
        afr[_mi] = _cv.s;                                                      \
    }                                                                          \
} while (0)

// read B-frags (4 n-tiles) from LDS buf b_
#define BRD(bfr, b_) do {                                                      \
    _Pragma("unroll")                                                          \
    for (int _nj = 0; _nj < 4; ++_nj)                                          \
        bfr[_nj] = *(const short8*)&bds[b_][_nj * 16 + lanelo][klo8];          \
} while (0)

#define MFMA16() do {                                                          \
    _Pragma("unroll")                                                          \
    for (int _mi = 0; _mi < 4; ++_mi)                                          \
        _Pragma("unroll")                                                      \
        for (int _nj = 0; _nj < 4; ++_nj)                                      \
            acc[_mi][_nj] = __builtin_amdgcn_mfma_f32_16x16x32_bf16(           \
                afr[_mi], bfr[_nj], acc[_mi][_nj], 0, 0, 0);                   \
} while (0)

// lgkmcnt-only barrier: LDS visibility without draining the w vmcnt FIFO
#define BARLDS() asm volatile("s_waitcnt lgkmcnt(0)\n\ts_barrier" ::: "memory")

// one step, parity q (compile-time): consume xw_q, issue (s+2) into q-sets,
// read B from buf q, MFMA, convert w(s+1) from other set -> buf 1-q.
#define STEP(xwq, wrq, xwo, wro, q_, ISS_, CVT_) do {                          \
    short8 afr[4], bfr[4];                                                     \
    AEXP(afr, xwq);                                                            \
    if (ISS_) { XISS(xwq); WISS(wrq); }                                        \
    BRD(bfr, q_);                                                              \
    MFMA16();                                                                  \
    if (CVT_) { WCVT(wro, 1 - (q_)); BARLDS(); }                               \
} while (0)

__global__ __launch_bounds__(512, 2) void evo_mfma(const float* __restrict__ w,
                                                   const uint32_t* __restrict__ xp,
                                                   float* __restrict__ out) {
    __shared__ __align__(16) uint16_t bds[2][OT][40];  // [buf][col][k32+pad8]
    __shared__ float cs_lds[8][64];

    const int tid    = threadIdx.x;
    const int lane   = tid & 63;
    const int wvid   = __builtin_amdgcn_readfirstlane(tid >> 6);  // 0..7
    const int lanelo = lane & 15;
    const int klo8   = (lane >> 4) * 8;       // k-offset within frag
    const int shamt  = (lane >> 4) * 8;       // byte shift in x-word
    const int p      = blockIdx.x >> 5;       // 0..15
    const int og     = blockIdx.x & 31;       // 0..31

    // w: this thread streams col og*64+lane, rows wvid*4+j (+32 per step)
    const float* w0n = w + (size_t)p * ((size_t)NI * NO)
                     + (size_t)(wvid * 4) * NO + og * OT + lane;
    const float* w1n = w0n + (size_t)NP * ((size_t)NI * NO);
    // x: per-lane row base for this wave's 4 m-frags (rows wvid*64+mi*16+lanelo)
    const uint32_t* xn = xp + ((size_t)p * NB + wvid * 64 + lanelo) * JW;

    f32x4 acc[4][4];
#pragma unroll
    for (int mi = 0; mi < 4; ++mi)
#pragma unroll
        for (int nj = 0; nj < 4; ++nj) acc[mi][nj] = (f32x4)0.0f;
    float cs = 0.0f;

    uint32_t xwA[4], xwB[4];
    float    wrA[8], wrB[8];

    // ---- prologue: issue steps 0,1; convert step 0 into buf 0 ----
    XISS(xwA); WISS(wrA);          // step 0
    XISS(xwB); WISS(wrB);          // step 1
    WCVT(wrA, 0);                  // waits w(0) only; w(1)/x(1) stay in flight
    BARLDS();

    // ---- 62 steps in 31 double-steps, then peel 62/63 ----
#pragma unroll 1
    for (int t = 0; t < 31; ++t) {
        STEP(xwA, wrA, xwB, wrB, 0, 1, 1);   // even step
        STEP(xwB, wrB, xwA, wrA, 1, 1, 1);   // odd step
    }
    STEP(xwA, wrA, xwB, wrB, 0, 0, 1);       // s=62: no issue, cvt w(63)
    STEP(xwB, wrB, xwA, wrA, 1, 0, 0);       // s=63: compute only

    // ---- colsum reduce + epilogue ----
    cs_lds[wvid][lane] = cs;
    __syncthreads();

    float* obase = out + ((size_t)p * NB + wvid * 64) * NO + og * OT;
#pragma unroll
    for (int nj = 0; nj < 4; ++nj) {
        const int colL = nj * 16 + lanelo;
        float csT = 0.0f;
#pragma unroll
        for (int wq = 0; wq < 8; ++wq) csT += cs_lds[wq][colL];
#pragma unroll
        for (int mi = 0; mi < 4; ++mi) {
            const int r0 = mi * 16 + (lane >> 4) * 4;
            const f32x4 v = acc[mi][nj];
            obase[(size_t)(r0 + 0) * NO + colL] = v[0] + csT;
            obase[(size_t)(r0 + 1) * NO + colL] = v[1] + csT;
            obase[(size_t)(r0 + 2) * NO + colL] = v[2] + csT;
            obase[(size_t)(r0 + 3) * NO + colL] = v[3] + csT;
        }
    }
}

extern "C" void kernel_launch(void* const* d_in, const int* in_sizes, int n_in,
                              void* d_out, int out_size, void* d_ws, size_t ws_size,
                              hipStream_t stream) {
    const float* x = (const float*)d_in[0];   // (16,512,2048) fp32 {0,1}
    const float* w = (const float*)d_in[1];   // (2,16,1,2048,2048) fp32 {0,1}
    float* out     = (float*)d_out;           // (16,512,2048) fp32
    uint32_t* xp   = (uint32_t*)d_ws;         // 2 MB packed x

    pack_x_kernel<<<dim3((NP * NB * 64) / 256), dim3(256), 0, stream>>>(x, xp);
    evo_mfma<<<dim3(NP * 32), dim3(512), 0, stream>>>(w, xp, out);
}

// Round 7
// 170.623 us; speedup vs baseline: 1.6306x; 1.3542x over previous
//
#include <hip/hip_runtime.h>
#include <stdint.h>

// out[p,b,o] = sum_i x*w0 + (1-x)*w1 = sum_i x*(w0-w1) + sum_i w1
// R15: MFMA formulation (R14, absmax-0-verified fragments) with the w-stream
// read in 512B-contiguous strips instead of 256B. Theory: every prior round
// read w as 256B granules @8KB stride -> ~2.4-3.5 TB/s DRAM efficiency; that
// stream IS the plateau (R14 stripped compute and still ran ~215us).
//   Grid 256 = 16p x 16og(128 cols), block 512 thr = 8 waves, 1 block/CU.
//   Wave wv: output rows wv*64..+63 (4 m-frags), all 128 cols (8 n-frags),
//   acc[4][8] f32x4 = 128 VGPR (2 waves/EU -> 256 budget).
//   Per step (32 k-rows): lane l loads cols 2l,2l+1 (float2 = wave-wide 512B
//   row strip), rows wv+8j, both mats; d=w0-w1 -> bf16 tile bds[col][40]
//   (b128 frag reads); colsum(w1) per-thread. w-prefetch 2 steps deep (dual
//   reg sets); barriers lgkmcnt-only (vmcnt FIFO never drained).

#define NP 16
#define NB 512
#define NI 2048
#define NO 2048
#define JW 64               // u32 words per i-row in xp
#define OT 128              // o-columns per block
#define KS 32               // k-rows per step
#define NST (NI / KS)       // 64 steps

typedef __attribute__((ext_vector_type(8))) short short8;
typedef __attribute__((ext_vector_type(4))) float f32x4;

__global__ __launch_bounds__(256) void pack_x_kernel(const float* __restrict__ x,
                                                     uint32_t* __restrict__ xp) {
    const int gtid = blockIdx.x * 256 + threadIdx.x;
    const int row  = gtid >> 6;     // p*NB + b
    const int lane = gtid & 63;
    const float* src = x + (size_t)row * NI;
    unsigned long long* dst = (unsigned long long*)(xp + (size_t)row * JW);
#pragma unroll 4
    for (int k = 0; k < NI / 64; ++k) {
        const float v = src[k * 64 + lane];
        const unsigned long long m = __ballot(v != 0.0f);
        if (lane == 0) dst[k] = m;
    }
}

// issue next step's w: 4 rows (wv+8j) x 2 cols x 2 mats, 512B wave strips
#define WISS(s0_, s1_) do {                                                    \
    _Pragma("unroll")                                                          \
    for (int _j = 0; _j < 4; ++_j) {                                           \
        s0_[_j] = *(const float2*)(w0n + (size_t)_j * 8 * NO);                 \
        s1_[_j] = *(const float2*)(w1n + (size_t)_j * 8 * NO);                 \
    }                                                                          \
    w0n += (size_t)KS * NO; w1n += (size_t)KS * NO;                            \
} while (0)

// convert a w set -> bf16 d tile in bds[b_], accumulate colsum(w1)
#define CVT(s0_, s1_, b_) do {                                                 \
    _Pragma("unroll")                                                          \
    for (int _j = 0; _j < 4; ++_j) {                                           \
        const int _kk = wv + 8 * _j;                                           \
        const float _d0 = s0_[_j].x - s1_[_j].x;                               \
        const float _d1 = s0_[_j].y - s1_[_j].y;                               \
        cs0 += s1_[_j].x; cs1 += s1_[_j].y;                                    \
        bds[b_][2 * lane][_kk]     = (uint16_t)(__float_as_uint(_d0) >> 16);   \
        bds[b_][2 * lane + 1][_kk] = (uint16_t)(__float_as_uint(_d1) >> 16);   \
    }                                                                          \
} while (0)

// issue next x words (4 m-frag rows' step-word) and bump
#define XISS(xw) do {                                                          \
    xw[0] = xn[0]; xw[1] = xn[1024]; xw[2] = xn[2048]; xw[3] = xn[3072];       \
    xn += 1;                                                                   \
} while (0)

// expand A-frags from packed-x words: bit -> bf16 {0,1}  (R14-verified)
#define AEXP(afr, xw) do {                                                     \
    _Pragma("unroll")                                                          \
    for (int _mi = 0; _mi < 4; ++_mi) {                                        \
        const uint32_t _by = (xw[_mi] >> klo8) & 0xFFu;                        \
        union { uint32_t u[4]; short8 s; } _cv;                                \
        _cv.u[0] = (_by & 1u   ? 0x3F80u : 0u) | (_by & 2u   ? 0x3F800000u : 0u); \
        _cv.u[1] = (_by & 4u   ? 0x3F80u : 0u) | (_by & 8u   ? 0x3F800000u : 0u); \
        _cv.u[2] = (_by & 16u  ? 0x3F80u : 0u) | (_by & 32u  ? 0x3F800000u : 0u); \
        _cv.u[3] = (_by & 64u  ? 0x3F80u : 0u) | (_by & 128u ? 0x3F800000u : 0u); \
        afr[_mi] = _cv.s;                                                      \
    }                                                                          \
} while (0)

// read B-frags from bds[b_] and do all 32 MFMAs of the step
#define BRDMFMA(afr, b_) do {                                                  \
    _Pragma("unroll")                                                          \
    for (int _nj = 0; _nj < 8; ++_nj) {                                        \
        const short8 _bf = *(const short8*)&bds[b_][_nj * 16 + lanelo][klo8];  \
        _Pragma("unroll")                                                      \
        for (int _mi = 0; _mi < 4; ++_mi)                                      \
            acc[_mi][_nj] = __builtin_amdgcn_mfma_f32_16x16x32_bf16(           \
                afr[_mi], _bf, acc[_mi][_nj], 0, 0, 0);                        \
    }                                                                          \
} while (0)

// lgkmcnt-only barrier: LDS visibility without draining the w vmcnt FIFO
#define BARLDS() asm volatile("s_waitcnt lgkmcnt(0)\n\ts_barrier" ::: "memory")

__global__ __launch_bounds__(512, 2) void evo_w2(const float* __restrict__ w,
                                                 const uint32_t* __restrict__ xp,
                                                 float* __restrict__ out) {
    __shared__ __align__(16) uint16_t bds[2][OT][40];  // 20 KB, dbuf d tile
    __shared__ float csl[8][64][2];                    // 4 KB, colsum partials

    const int tid    = threadIdx.x;
    const int lane   = tid & 63;
    const int wv     = __builtin_amdgcn_readfirstlane(tid >> 6);  // 0..7
    const int lanelo = lane & 15;
    const int klo8   = (lane >> 4) * 8;
    const int p      = blockIdx.x >> 4;   // 0..15
    const int og     = blockIdx.x & 15;   // 0..15

    const size_t wq = (size_t)NI * NO;
    const float* w0n = w + (size_t)p * wq + (size_t)wv * NO + og * OT + 2 * lane;
    const float* w1n = w0n + (size_t)NP * wq;
    const uint32_t* xn = xp + ((size_t)p * NB + wv * 64 + lanelo) * JW;

    f32x4 acc[4][8];
#pragma unroll
    for (int mi = 0; mi < 4; ++mi)
#pragma unroll
        for (int nj = 0; nj < 8; ++nj) acc[mi][nj] = (f32x4)0.0f;
    float cs0 = 0.0f, cs1 = 0.0f;

    float2 wA0[4], wA1[4], wB0[4], wB1[4];
    uint32_t xwA[4], xwB[4];

    // ---- prologue: w(0),w(1),x(0),x(1) in flight; cvt w(0)->buf0; w(2) ----
    WISS(wA0, wA1);               // w(0)
    WISS(wB0, wB1);               // w(1)
    XISS(xwA); XISS(xwB);         // x(0), x(1)
    CVT(wA0, wA1, 0);             // waits w(0) only
    WISS(wA0, wA1);               // w(2)
    BARLDS();

    // ---- 64 steps, 2 per iter; w issue->cvt distance = 2 full steps ----
#pragma unroll 1
    for (int ss = 0; ss < 32; ++ss) {
        {   // even step s = 2ss : buf0, xwA
            short8 afr[4];
            AEXP(afr, xwA);
            if (ss < 31) XISS(xwA);            // x(2ss+2)
            BRDMFMA(afr, 0);
            CVT(wB0, wB1, 1);                  // w(2ss+1) -> buf1
            if (ss < 31) WISS(wB0, wB1);       // w(2ss+3)
            BARLDS();
        }
        {   // odd step s = 2ss+1 : buf1, xwB
            short8 afr[4];
            AEXP(afr, xwB);
            if (ss < 31) XISS(xwB);            // x(2ss+3)
            BRDMFMA(afr, 1);
            if (ss < 31) {
                CVT(wA0, wA1, 0);              // w(2ss+2) -> buf0
                if (ss < 30) WISS(wA0, wA1);   // w(2ss+4), last valid = w62
                BARLDS();
            }
        }
    }

    // ---- colsum reduce + epilogue (exact: integers <= 2048) ----
    csl[wv][lane][0] = cs0; csl[wv][lane][1] = cs1;
    __syncthreads();

    float* obase = out + ((size_t)p * NB + wv * 64) * NO + og * OT;
#pragma unroll
    for (int nj = 0; nj < 8; ++nj) {
        const int colT = nj * 16 + lanelo;
        float csT = 0.0f;
#pragma unroll
        for (int q = 0; q < 8; ++q) csT += csl[q][colT >> 1][colT & 1];
#pragma unroll
        for (int mi = 0; mi < 4; ++mi) {
            const int r0 = mi * 16 + (lane >> 4) * 4;
            const f32x4 v = acc[mi][nj];
            obase[(size_t)(r0 + 0) * NO + colT] = v[0] + csT;
            obase[(size_t)(r0 + 1) * NO + colT] = v[1] + csT;
            obase[(size_t)(r0 + 2) * NO + colT] = v[2] + csT;
            obase[(size_t)(r0 + 3) * NO + colT] = v[3] + csT;
        }
    }
}

extern "C" void kernel_launch(void* const* d_in, const int* in_sizes, int n_in,
                              void* d_out, int out_size, void* d_ws, size_t ws_size,
                              hipStream_t stream) {
    const float* x = (const float*)d_in[0];   // (16,512,2048) fp32 {0,1}
    const float* w = (const float*)d_in[1];   // (2,16,1,2048,2048) fp32 {0,1}
    float* out     = (float*)d_out;           // (16,512,2048) fp32
    uint32_t* xp   = (uint32_t*)d_ws;         // 2 MB packed x

    pack_x_kernel<<<dim3((NP * NB * 64) / 256), dim3(256), 0, stream>>>(x, xp);
    evo_w2<<<dim3(NP * (NO / OT)), dim3(512), 0, stream>>>(w, xp, out);
}

// Round 8
// 162.629 us; speedup vs baseline: 1.7108x; 1.0492x over previous
//
#include <hip/hip_runtime.h>
#include <stdint.h>

// out[p,b,o] = sum_i x*w0 + (1-x)*w1 = sum_i x*(w0-w1) + sum_i w1
// R16: MFMA formulation (R14/R15-verified fragments) with the w-stream in
// 1024B-contiguous strips (R15's 512B gave 231->170us; same lever, doubled).
//   Grid 256 = (tile t = 16p x 8og(256 cols)) x (h = b-half), 1 block/CU.
//   Blocks t and t+128 (same XCD under bid%8 round-robin) read the SAME w
//   tile in the same step order -> requests merge in the XCD's L2 (window
//   ~64KB/step/pair << 256KB L2 budget/pair) -> w fetched from HBM ~once.
//   Block: 512 thr = 8 waves; wave wv owns b-rows h*256+wv*32..+31
//   (2 m-frags) x 256 cols (16 n-frags); acc[2][16] f32x4 = 128 VGPR.
//   Per step (32 k): wave wv loads k-rows 4wv..4wv+3, both mats, lane l
//   cols 4l..4l+3 (f32x4 = wave-wide 1024B strip); d=w0-w1 -> bf16 tile
//   bds[col][44] (pitch 88B: B-frag b64 reads ~2-way conflict-free; writes
//   one b64 per col, 4-way). colsum(w1) per-thread. 2-step-deep w prefetch,
//   lgkmcnt-only barriers (vmcnt FIFO never drained).

#define NP 16
#define NB 512
#define NI 2048
#define NO 2048
#define JW 64               // u32 words per i-row in xp
#define OT 256              // o-columns per block
#define KS 32               // k-rows per step
#define NST (NI / KS)       // 64 steps

typedef __attribute__((ext_vector_type(8))) short short8;
typedef __attribute__((ext_vector_type(4))) float f32x4;

__global__ __launch_bounds__(256) void pack_x_kernel(const float* __restrict__ x,
                                                     uint32_t* __restrict__ xp) {
    const int gtid = blockIdx.x * 256 + threadIdx.x;
    const int row  = gtid >> 6;     // p*NB + b
    const int lane = gtid & 63;
    const float* src = x + (size_t)row * NI;
    unsigned long long* dst = (unsigned long long*)(xp + (size_t)row * JW);
#pragma unroll 4
    for (int k = 0; k < NI / 64; ++k) {
        const float v = src[k * 64 + lane];
        const unsigned long long m = __ballot(v != 0.0f);
        if (lane == 0) dst[k] = m;
    }
}

// bf16 truncation (exact for d in {-1,0,1} and w1 in {0,1})
#define BF16(f) ((uint32_t)(__float_as_uint(f) >> 16))

// issue next step's w: k-rows 4wv..4wv+3, lane cols 4l..4l+3, both mats
#define WISS(s0_, s1_) do {                                                    \
    _Pragma("unroll")                                                          \
    for (int _j = 0; _j < 4; ++_j) {                                           \
        s0_[_j] = *(const f32x4*)(w0n + (size_t)_j * NO);                      \
        s1_[_j] = *(const f32x4*)(w1n + (size_t)_j * NO);                      \
    }                                                                          \
    w0n += (size_t)KS * NO; w1n += (size_t)KS * NO;                            \
} while (0)

// convert a w set -> bf16 d tile rows 4wv..+3 of bds[b_]; colsum(w1).
// One b64 write per col (4 consecutive k packed).
#define CVT(s0_, s1_, b_) do {                                                 \
    _Pragma("unroll")                                                          \
    for (int _c = 0; _c < 4; ++_c) {                                           \
        const float _d0 = s0_[0][_c] - s1_[0][_c];                             \
        const float _d1 = s0_[1][_c] - s1_[1][_c];                             \
        const float _d2 = s0_[2][_c] - s1_[2][_c];                             \
        const float _d3 = s0_[3][_c] - s1_[3][_c];                             \
        cs[_c] += s1_[0][_c] + s1_[1][_c] + s1_[2][_c] + s1_[3][_c];           \
        uint2 _st;                                                             \
        _st.x = BF16(_d0) | (BF16(_d1) << 16);                                 \
        _st.y = BF16(_d2) | (BF16(_d3) << 16);                                 \
        *(uint2*)&bds[b_][4 * lane + _c][4 * wv] = _st;                        \
    }                                                                          \
} while (0)

// issue next x words (2 m-frag rows' step-word) and bump
#define XISS(xw) do {                                                          \
    xw[0] = xn[0]; xw[1] = xn[1024];                                           \
    xn += 1;                                                                   \
} while (0)

// expand A-frags from packed-x words: bit -> bf16 {0,1}  (R14-verified)
#define AEXP(afr, xw) do {                                                     \
    _Pragma("unroll")                                                          \
    for (int _mi = 0; _mi < 2; ++_mi) {                                        \
        const uint32_t _by = (xw[_mi] >> klo8) & 0xFFu;                        \
        union { uint32_t u[4]; short8 s; } _cv;                                \
        _cv.u[0] = (_by & 1u   ? 0x3F80u : 0u) | (_by & 2u   ? 0x3F800000u : 0u); \
        _cv.u[1] = (_by & 4u   ? 0x3F80u : 0u) | (_by & 8u   ? 0x3F800000u : 0u); \
        _cv.u[2] = (_by & 16u  ? 0x3F80u : 0u) | (_by & 32u  ? 0x3F800000u : 0u); \
        _cv.u[3] = (_by & 64u  ? 0x3F80u : 0u) | (_by & 128u ? 0x3F800000u : 0u); \
        afr[_mi] = _cv.s;                                                      \
    }                                                                          \
} while (0)

// read B-frags from bds[b_] (two b64s each; pitch 88B -> ~2-way, free) + MFMA
#define BRDMFMA(afr, b_) do {                                                  \
    _Pragma("unroll")                                                          \
    for (int _nj = 0; _nj < 16; ++_nj) {                                       \
        union { uint2 q[2]; short8 s; } _u;                                    \
        _u.q[0] = *(const uint2*)&bds[b_][_nj * 16 + lanelo][klo8];            \
        _u.q[1] = *(const uint2*)&bds[b_][_nj * 16 + lanelo][klo8 + 4];        \
        _Pragma("unroll")                                                      \
        for (int _mi = 0; _mi < 2; ++_mi)                                      \
            acc[_mi][_nj] = __builtin_amdgcn_mfma_f32_16x16x32_bf16(           \
                afr[_mi], _u.s, acc[_mi][_nj], 0, 0, 0);                       \
    }                                                                          \
} while (0)

// lgkmcnt-only barrier: LDS visibility without draining the w vmcnt FIFO
#define BARLDS() asm volatile("s_waitcnt lgkmcnt(0)\n\ts_barrier" ::: "memory")

__global__ __launch_bounds__(512, 2) void evo_w4(const float* __restrict__ w,
                                                 const uint32_t* __restrict__ xp,
                                                 float* __restrict__ out) {
    __shared__ __align__(16) uint16_t bds[2][OT][44];  // 44 KB, dbuf d tile
    __shared__ float csl[8][64][4];                    // 8 KB, colsum partials

    const int tid    = threadIdx.x;
    const int lane   = tid & 63;
    const int wv     = __builtin_amdgcn_readfirstlane(tid >> 6);  // 0..7
    const int lanelo = lane & 15;
    const int klo8   = (lane >> 4) * 8;
    const int h      = blockIdx.x >> 7;         // b-half 0..1
    const int t      = blockIdx.x & 127;        // tile; pair (t, t+128) same XCD
    const int p      = t >> 3;                  // 0..15
    const int og     = t & 7;                   // 0..7

    const size_t wq = (size_t)NI * NO;
    const float* w0n = w + (size_t)p * wq + (size_t)(4 * wv) * NO
                     + og * OT + 4 * lane;
    const float* w1n = w0n + (size_t)NP * wq;
    const uint32_t* xn = xp + ((size_t)p * NB + h * 256 + wv * 32 + lanelo) * JW;

    f32x4 acc[2][16];
#pragma unroll
    for (int mi = 0; mi < 2; ++mi)
#pragma unroll
        for (int nj = 0; nj < 16; ++nj) acc[mi][nj] = (f32x4)0.0f;
    float cs[4] = {0.0f, 0.0f, 0.0f, 0.0f};

    f32x4 wA0[4], wA1[4], wB0[4], wB1[4];
    uint32_t xwA[2], xwB[2];

    // ---- prologue: w(0),w(1),x(0),x(1) in flight; cvt w(0)->buf0; w(2) ----
    WISS(wA0, wA1);               // w(0)
    WISS(wB0, wB1);               // w(1)
    XISS(xwA); XISS(xwB);         // x(0), x(1)
    CVT(wA0, wA1, 0);             // waits w(0) only
    WISS(wA0, wA1);               // w(2)
    BARLDS();

    // ---- 64 steps, 2/iter; w issue->cvt distance = 2 full steps ----
#pragma unroll 1
    for (int ss = 0; ss < 32; ++ss) {
        {   // even step s = 2ss : buf0, xwA
            short8 afr[2];
            AEXP(afr, xwA);
            if (ss < 31) XISS(xwA);            // x(2ss+2)
            BRDMFMA(afr, 0);
            CVT(wB0, wB1, 1);                  // w(2ss+1) -> buf1
            if (ss < 31) WISS(wB0, wB1);       // w(2ss+3)
            BARLDS();
        }
        {   // odd step s = 2ss+1 : buf1, xwB
            short8 afr[2];
            AEXP(afr, xwB);
            if (ss < 31) XISS(xwB);            // x(2ss+3)
            BRDMFMA(afr, 1);
            if (ss < 31) {
                CVT(wA0, wA1, 0);              // w(2ss+2) -> buf0
                if (ss < 30) WISS(wA0, wA1);   // w(2ss+4), last valid = w62
                BARLDS();
            }
        }
    }

    // ---- colsum reduce + epilogue (exact: integers <= 2048) ----
    csl[wv][lane][0] = cs[0]; csl[wv][lane][1] = cs[1];
    csl[wv][lane][2] = cs[2]; csl[wv][lane][3] = cs[3];
    __syncthreads();

    float* obase = out + ((size_t)p * NB + h * 256 + wv * 32) * NO + og * OT;
#pragma unroll
    for (int nj = 0; nj < 16; ++nj) {
        const int colT = nj * 16 + lanelo;
        float csT = 0.0f;
#pragma unroll
        for (int q = 0; q < 8; ++q) csT += csl[q][colT >> 2][colT & 3];
#pragma unroll
        for (int mi = 0; mi < 2; ++mi) {
            const int r0 = mi * 16 + (lane >> 4) * 4;
            const f32x4 v = acc[mi][nj];
            obase[(size_t)(r0 + 0) * NO + colT] = v[0] + csT;
            obase[(size_t)(r0 + 1) * NO + colT] = v[1] + csT;
            obase[(size_t)(r0 + 2) * NO + colT] = v[2] + csT;
            obase[(size_t)(r0 + 3) * NO + colT] = v[3] + csT;
        }
    }
}

extern "C" void kernel_launch(void* const* d_in, const int* in_sizes, int n_in,
                              void* d_out, int out_size, void* d_ws, size_t ws_size,
                              hipStream_t stream) {
    const float* x = (const float*)d_in[0];   // (16,512,2048) fp32 {0,1}
    const float* w = (const float*)d_in[1];   // (2,16,1,2048,2048) fp32 {0,1}
    float* out     = (float*)d_out;           // (16,512,2048) fp32
    uint32_t* xp   = (uint32_t*)d_ws;         // 2 MB packed x

    pack_x_kernel<<<dim3((NP * NB * 64) / 256), dim3(256), 0, stream>>>(x, xp);
    evo_w4<<<dim3(256), dim3(512), 0, stream>>>(w, xp, out);
}